// Round 5
// baseline (186.308 us; speedup 1.0000x reference)
//
#include <hip/hip_runtime.h>

// Bidirectional LSTM, B=16384 T=512 I=1 H=8, + final linear on [h_f(T-1), h_b(T-1)].
// Backward direction's state at time T-1 is its FIRST scan step -> one step only.
//
// R5: 8 lanes/element, ZERO LDS/DS ops in the steady-state loop, minimal trans ops.
//  - h-broadcast: 9 DPP moves (row_half_mirror + 8 quad_perm bcasts). Per-quad
//    slot order q0:{0,1,2,3,7,6,5,4} / q1:{4,5,6,7,3,2,1,0} compensated by a
//    weight permutation computed with scalar index arithmetic at setup (no
//    arrays -> no scratch, unlike R4).
//  - gates: e = exp2(z') via packed VALU exp2 (magic rndne + deg-5 Taylor on
//    [-0.5,0.5] + integer ldexp), evaluated on (i,f) and (g,o) pairs with
//    v_pk_* ops. Activation scales folded into weights: rows i,f,o get
//    -log2(e) (sigma = 1/(1+e)); row g gets +2*log2(e) (tanh = 1-2/(1+e)).
//  - all 4 gate divides via 2 v_rcp (paired-reciprocal trick).
//  - tanh(c) via v_exp + v_rcp (shortest serial tail).
// Trans ops per lane-step: 3 rcp + 1 exp (was 10 in R1 = the dominant issue cost).

typedef float f32x2 __attribute__((ext_vector_type(2)));

#define LOG2E 1.4426950408889634f

// DPP move: 0x141 = row_half_mirror (8-group preserving); quad_perm bcast k = k*0x55.
#define DPPF(v, ctrl) __int_as_float(__builtin_amdgcn_update_dpp(0, __float_as_int(v), (ctrl), 0xF, 0xF, true))

__device__ __forceinline__ f32x2 pk_add(f32x2 a, f32x2 b) {
    f32x2 d; asm("v_pk_add_f32 %0, %1, %2" : "=v"(d) : "v"(a), "v"(b)); return d;
}
__device__ __forceinline__ f32x2 pk_mul(f32x2 a, f32x2 b) {
    f32x2 d; asm("v_pk_mul_f32 %0, %1, %2" : "=v"(d) : "v"(a), "v"(b)); return d;
}
__device__ __forceinline__ f32x2 pk_fma(f32x2 a, f32x2 b, f32x2 c) {
    asm("v_pk_fma_f32 %0, %1, %2, %0" : "+v"(c) : "v"(a), "v"(b)); return c;
}

// exp2 constants (Taylor of 2^f = e^{f ln2}; |f|<=0.5 -> rel err ~2.4e-6 at deg 5)
#define EXP2_MAGIC 12582912.0f              // 1.5 * 2^23, bits 0x4B400000
#define EXP2_KADJ  (127 - 0x4B400000)       // (as_int(y)+KADJ)<<23 = 2^n bits

struct ExpK {
    f32x2 M2, nM2, n1, one2, c1, c2, c3, c4, c5;
};

// packed exp2 on both halves of z (z must be in [-120, 120]; here |z| < ~60)
__device__ __forceinline__ f32x2 exp2_pair(f32x2 z, const ExpK& E) {
    f32x2 y = pk_add(z, E.M2);           // round-to-nearest int in low mantissa bits
    f32x2 n = pk_add(y, E.nM2);          // n = rndne(z) as float
    f32x2 f = pk_fma(n, E.n1, z);        // f = z - n in [-0.5, 0.5]
    f32x2 p = pk_fma(f, E.c5, E.c4);     // deg-5 Horner
    p = pk_fma(p, f, E.c3);
    p = pk_fma(p, f, E.c2);
    p = pk_fma(p, f, E.c1);
    p = pk_fma(p, f, E.one2);            // p ~= 2^f
    int s0 = (__float_as_int(y[0]) + EXP2_KADJ) << 23;   // 2^n exponent bits
    int s1 = (__float_as_int(y[1]) + EXP2_KADJ) << 23;
    f32x2 s;
    s[0] = __int_as_float(s0);
    s[1] = __int_as_float(s1);
    return pk_mul(p, s);
}

struct Ctx {
    f32x2 wk[4][4];   // [row r=i,f,g,o][slot pair p], pre-scaled + quad-permuted
    f32x2 wxb[4];     // {wx'[r], b'[r]}  (init acc via pk_mul with {x, 1})
};

__device__ __forceinline__ void load_ctx(Ctx& C, int j, int qp,
    const float* __restrict__ w_ih, const float* __restrict__ w_hh,
    const float* __restrict__ b)
{
    // slot s -> h index: s<4: 4*qp+s ; s>=4: (4-4*qp)+(7-s)  (matches DPP delivery)
    int base = qp * 4;
    int ob = 4 - base;
    int i0 = base, i1 = base + 1, i2 = base + 2, i3 = base + 3;
    int i4 = ob + 3, i5 = ob + 2, i6 = ob + 1, i7 = ob;

    const float sc[4]  = {-LOG2E, -LOG2E, 2.0f * LOG2E, -LOG2E};
    const int rows[4] = {j, 8 + j, 16 + j, 24 + j};
#pragma unroll
    for (int r = 0; r < 4; ++r) {
        const float* wr = w_hh + rows[r] * 8;
        float s = sc[r];
        C.wk[r][0] = f32x2{wr[i0] * s, wr[i1] * s};
        C.wk[r][1] = f32x2{wr[i2] * s, wr[i3] * s};
        C.wk[r][2] = f32x2{wr[i4] * s, wr[i5] * s};
        C.wk[r][3] = f32x2{wr[i6] * s, wr[i7] * s};
        C.wxb[r] = f32x2{w_ih[rows[r]] * s, b[rows[r]] * s};
    }
}

__device__ __forceinline__ void lstm_step(f32x2 xp, float& h, float& c,
                                          const Ctx& C, const ExpK& E)
{
    // all-VALU broadcast of the 8 h values of this 8-lane group
    float hm = DPPF(h, 0x141);   // row_half_mirror
    f32x2 hp0, hp1, hp2, hp3;
    hp0[0] = DPPF(h,  0x00); hp0[1] = DPPF(h,  0x55);
    hp1[0] = DPPF(h,  0xAA); hp1[1] = DPPF(h,  0xFF);
    hp2[0] = DPPF(hm, 0x00); hp2[1] = DPPF(hm, 0x55);
    hp3[0] = DPPF(hm, 0xAA); hp3[1] = DPPF(hm, 0xFF);

    f32x2 a0 = pk_mul(xp, C.wxb[0]);   // {wx*x, b} partial pairs
    f32x2 a1 = pk_mul(xp, C.wxb[1]);
    f32x2 a2 = pk_mul(xp, C.wxb[2]);
    f32x2 a3 = pk_mul(xp, C.wxb[3]);
    a0 = pk_fma(hp0, C.wk[0][0], a0); a1 = pk_fma(hp0, C.wk[1][0], a1);
    a2 = pk_fma(hp0, C.wk[2][0], a2); a3 = pk_fma(hp0, C.wk[3][0], a3);
    a0 = pk_fma(hp1, C.wk[0][1], a0); a1 = pk_fma(hp1, C.wk[1][1], a1);
    a2 = pk_fma(hp1, C.wk[2][1], a2); a3 = pk_fma(hp1, C.wk[3][1], a3);
    a0 = pk_fma(hp2, C.wk[0][2], a0); a1 = pk_fma(hp2, C.wk[1][2], a1);
    a2 = pk_fma(hp2, C.wk[2][2], a2); a3 = pk_fma(hp2, C.wk[3][2], a3);
    a0 = pk_fma(hp3, C.wk[0][3], a0); a1 = pk_fma(hp3, C.wk[1][3], a1);
    a2 = pk_fma(hp3, C.wk[2][3], a2); a3 = pk_fma(hp3, C.wk[3][3], a3);

    f32x2 zif, zgo;                      // scaled pre-activations
    zif[0] = a0[0] + a0[1];              // z'_i
    zif[1] = a1[0] + a1[1];              // z'_f
    zgo[0] = a2[0] + a2[1];              // z'_g
    zgo[1] = a3[0] + a3[1];              // z'_o

    f32x2 eif = exp2_pair(zif, E);
    f32x2 ego = exp2_pair(zgo, E);
    f32x2 dif = pk_add(eif, E.one2);     // 1+e
    f32x2 dgo = pk_add(ego, E.one2);

    // paired reciprocals: 2 rcp for 4 gates
    float R1 = __builtin_amdgcn_rcpf(dif[0] * dif[1]);
    float qi = R1 * dif[1];              // sigma(i)
    float qf = R1 * dif[0];              // sigma(f)
    float R2 = __builtin_amdgcn_rcpf(dgo[0] * dgo[1]);
    float qg = R2 * dgo[1];              // 1/(1+e^{2g})
    float qo = R2 * dgo[0];              // sigma(o)

    float tg = fmaf(-2.0f, qg, 1.0f);    // tanh(g)
    c = fmaf(qf, c, qi * tg);
    // tanh(c) = 1 - 2/(1+e^{2c})
    float ec = __builtin_amdgcn_exp2f(c * (2.0f * LOG2E));
    float qc = __builtin_amdgcn_rcpf(1.0f + ec);
    h = qo * fmaf(-2.0f, qc, 1.0f);
}

__global__ __launch_bounds__(256, 2) void bilstm_kernel(
    const float* __restrict__ x, const float* __restrict__ h0, const float* __restrict__ c0,
    const float* __restrict__ w_ih_f, const float* __restrict__ w_hh_f, const float* __restrict__ b_f,
    const float* __restrict__ w_ih_b, const float* __restrict__ w_hh_b, const float* __restrict__ b_b,
    const float* __restrict__ w_lin, const float* __restrict__ b_lin,
    float* __restrict__ out, int B, int T)
{
    int tid = blockIdx.x * 256 + threadIdx.x;
    int b = tid >> 3;
    int j = tid & 7;
    int qp = (threadIdx.x >> 2) & 1;     // quad parity within the 8-lane group
    if (b >= B) return;

    ExpK E;
    E.M2   = f32x2{EXP2_MAGIC, EXP2_MAGIC};
    E.nM2  = f32x2{-EXP2_MAGIC, -EXP2_MAGIC};
    E.n1   = f32x2{-1.0f, -1.0f};
    E.one2 = f32x2{1.0f, 1.0f};
    E.c1   = f32x2{0.6931471805599453f, 0.6931471805599453f};
    E.c2   = f32x2{0.2402265069591007f, 0.2402265069591007f};
    E.c3   = f32x2{0.0555041086648216f, 0.0555041086648216f};
    E.c4   = f32x2{0.0096181291076285f, 0.0096181291076285f};
    E.c5   = f32x2{0.0013333558146428f, 0.0013333558146428f};

    Ctx Cf;
    load_ctx(Cf, j, qp, w_ih_f, w_hh_f, b_f);

    float h = h0[(size_t)b * 8 + j];
    float c = c0[(size_t)b * 8 + j];

    f32x2 xp;
    xp[1] = 1.0f;

    const float4* xr = (const float4*)(x + (size_t)b * T);
    int nT4 = T >> 2;
    for (int t4 = 0; t4 < nT4; ++t4) {
        float4 xv = xr[t4];
        xp[0] = xv.x; lstm_step(xp, h, c, Cf, E);
        xp[0] = xv.y; lstm_step(xp, h, c, Cf, E);
        xp[0] = xv.z; lstm_step(xp, h, c, Cf, E);
        xp[0] = xv.w; lstm_step(xp, h, c, Cf, E);
    }

    // backward direction: exactly one step on x[:, T-1]
    Ctx Cb;
    load_ctx(Cb, j, qp, w_ih_b, w_hh_b, b_b);
    float hb = h0[(size_t)B * 8 + (size_t)b * 8 + j];
    float cb = c0[(size_t)B * 8 + (size_t)b * 8 + j];
    xp[0] = x[(size_t)b * T + (T - 1)];
    lstm_step(xp, hb, cb, Cb, E);

    // final linear: out[b] = sum_j h[j]*wl[j] + hb[j]*wl[8+j] + b_lin
    float part = fmaf(h, w_lin[j], hb * w_lin[8 + j]);
    part += __shfl_xor(part, 1, 8);
    part += __shfl_xor(part, 2, 8);
    part += __shfl_xor(part, 4, 8);
    if (j == 0) out[b] = part + b_lin[0];
}

extern "C" void kernel_launch(void* const* d_in, const int* in_sizes, int n_in,
                              void* d_out, int out_size, void* d_ws, size_t ws_size,
                              hipStream_t stream)
{
    const float* x      = (const float*)d_in[0];
    const float* h0     = (const float*)d_in[1];
    const float* c0     = (const float*)d_in[2];
    const float* w_ih_f = (const float*)d_in[3];
    const float* w_hh_f = (const float*)d_in[4];
    const float* b_f    = (const float*)d_in[5];
    const float* w_ih_b = (const float*)d_in[6];
    const float* w_hh_b = (const float*)d_in[7];
    const float* b_b    = (const float*)d_in[8];
    const float* w_lin  = (const float*)d_in[9];
    const float* b_lin  = (const float*)d_in[10];
    float* out = (float*)d_out;

    int B = in_sizes[1] / 16;   // h0: (2, B, 8)
    int T = in_sizes[0] / B;    // x:  (B, T, 1)

    int threads = B * 8;
    dim3 block(256);
    dim3 grid((threads + 255) / 256);
    hipLaunchKernelGGL(bilstm_kernel, grid, block, 0, stream,
                       x, h0, c0, w_ih_f, w_hh_f, b_f, w_ih_b, w_hh_b, b_b,
                       w_lin, b_lin, out, B, T);
}

// Round 6
// 147.012 us; speedup vs baseline: 1.2673x; 1.2673x over previous
//
#include <hip/hip_runtime.h>

// Bidirectional LSTM, B=16384 T=512 I=1 H=8, + final linear on [h_f(T-1), h_b(T-1)].
// Backward direction's state at time T-1 is its FIRST scan step -> one step only.
//
// R6 = R1 structure (plain scalar fma, hardware v_exp/v_rcp, compiler-scheduled)
// with three surgical fixes:
//  1. h-broadcast via 9 DPP movs (row_half_mirror + 8 quad_perm bcasts) instead
//     of 8 ds_swizzle -> no DS ops on the serial chain. Per-quad slot order
//     q0:{0,1,2,3,7,6,5,4} / q1:{4,5,6,7,3,2,1,0} compensated by permuting the
//     recurrent weights at setup with scalar index arithmetic (no arrays -> no
//     scratch spill, which is what killed R4).
//  2. Trans ops 10 -> 8 per step: activation scales folded into the weights
//     (i,f,o rows x -log2(e); g row x +2log2(e)); paired reciprocals (1 rcp
//     serves 2 gates); cell state kept pre-scaled by 2log2(e) so tanh(c)'s
//     exp argument is the cell register itself.
//  3. x float4 prefetched one iteration ahead.

#define LOG2E 1.4426950408889634f

// DPP move: 0x141 = row_half_mirror (8-group preserving); quad_perm bcast k = k*0x55.
#define DPPF(v, ctrl) __int_as_float(__builtin_amdgcn_update_dpp(0, __float_as_int(v), (ctrl), 0xF, 0xF, true))

struct Ctx {
    float wi[8], wf[8], wg[8], wo[8];  // recurrent rows, pre-scaled + slot-permuted
    float xi, xf, xg, xo;              // input weights, pre-scaled
    float bi, bf, bg, bo;              // biases, pre-scaled
};

__device__ __forceinline__ void load_ctx(Ctx& C, int j, int qp,
    const float* __restrict__ w_ih, const float* __restrict__ w_hh,
    const float* __restrict__ b)
{
    // DPP delivery order: slot s<4 -> h[qp*4+s]; slot s>=4 -> h[(4-qp*4)+(7-s)]
    int base = qp * 4;
    int ob = 4 - base;
    const float si = -LOG2E;           // sigma rows: e = exp2(-z*log2e) = e^-z
    const float sg = 2.0f * LOG2E;     // tanh row:  e = exp2(2z*log2e) = e^{2z}

    const float* ri = w_hh + (size_t)j * 8;
    const float* rf = w_hh + (size_t)(8 + j) * 8;
    const float* rg = w_hh + (size_t)(16 + j) * 8;
    const float* ro = w_hh + (size_t)(24 + j) * 8;
#pragma unroll
    for (int k = 0; k < 8; ++k) {
        int src = (k < 4) ? (base + k) : (ob + 7 - k);
        C.wi[k] = ri[src] * si;
        C.wf[k] = rf[src] * si;
        C.wg[k] = rg[src] * sg;
        C.wo[k] = ro[src] * si;
    }
    C.xi = w_ih[j] * si;      C.bi = b[j] * si;
    C.xf = w_ih[8 + j] * si;  C.bf = b[8 + j] * si;
    C.xg = w_ih[16 + j] * sg; C.bg = b[16 + j] * sg;
    C.xo = w_ih[24 + j] * si; C.bo = b[24 + j] * si;
}

// cs is the cell state pre-scaled by 2*log2(e).
__device__ __forceinline__ void lstm_step(float xt, float& h, float& cs, const Ctx& C)
{
    // all-VALU broadcast of the 8 h values of this 8-lane group
    float hm = DPPF(h, 0x141);  // row_half_mirror
    float hk[8];
    hk[0] = DPPF(h,  0x00); hk[1] = DPPF(h,  0x55);
    hk[2] = DPPF(h,  0xAA); hk[3] = DPPF(h,  0xFF);
    hk[4] = DPPF(hm, 0x00); hk[5] = DPPF(hm, 0x55);
    hk[6] = DPPF(hm, 0xAA); hk[7] = DPPF(hm, 0xFF);

    float zi = fmaf(xt, C.xi, C.bi);
    float zf = fmaf(xt, C.xf, C.bf);
    float zg = fmaf(xt, C.xg, C.bg);
    float zo = fmaf(xt, C.xo, C.bo);
#pragma unroll
    for (int k = 0; k < 8; ++k) {
        zi = fmaf(hk[k], C.wi[k], zi);
        zf = fmaf(hk[k], C.wf[k], zf);
        zg = fmaf(hk[k], C.wg[k], zg);
        zo = fmaf(hk[k], C.wo[k], zo);
    }

    float ei = __builtin_amdgcn_exp2f(zi);   // e^{-i}
    float ef = __builtin_amdgcn_exp2f(zf);   // e^{-f}
    float eg = __builtin_amdgcn_exp2f(zg);   // e^{2g}
    float eo = __builtin_amdgcn_exp2f(zo);   // e^{-o}
    float di = 1.0f + ei, df = 1.0f + ef;
    float dg = 1.0f + eg, dz = 1.0f + eo;

    // paired reciprocals: 2 rcp for 4 gates
    float Ra = __builtin_amdgcn_rcpf(di * df);
    float sigi = Ra * df;                    // sigma(i)
    float sigf = Ra * di;                    // sigma(f)
    float Rb = __builtin_amdgcn_rcpf(dg * dz);
    float qg   = Rb * dz;                    // 1/(1+e^{2g})
    float sigo = Rb * dg;                    // sigma(o)

    // tgs = 2*log2(e) * tanh(g)
    float tgs = fmaf(-4.0f * LOG2E, qg, 2.0f * LOG2E);
    cs = fmaf(sigf, cs, sigi * tgs);         // scaled cell update
    // tanh(c) = 1 - 2/(1+e^{2c}), and e^{2c} = exp2(cs)
    float ec = __builtin_amdgcn_exp2f(cs);
    float qc = __builtin_amdgcn_rcpf(1.0f + ec);
    h = sigo * fmaf(-2.0f, qc, 1.0f);
}

__global__ __launch_bounds__(256, 2) void bilstm_kernel(
    const float* __restrict__ x, const float* __restrict__ h0, const float* __restrict__ c0,
    const float* __restrict__ w_ih_f, const float* __restrict__ w_hh_f, const float* __restrict__ b_f,
    const float* __restrict__ w_ih_b, const float* __restrict__ w_hh_b, const float* __restrict__ b_b,
    const float* __restrict__ w_lin, const float* __restrict__ b_lin,
    float* __restrict__ out, int B, int T)
{
    int tid = blockIdx.x * 256 + threadIdx.x;
    int b = tid >> 3;
    int j = tid & 7;
    int qp = (threadIdx.x >> 2) & 1;   // quad parity within the 8-lane group
    if (b >= B) return;

    Ctx Cf;
    load_ctx(Cf, j, qp, w_ih_f, w_hh_f, b_f);

    float h  = h0[(size_t)b * 8 + j];
    float cs = c0[(size_t)b * 8 + j] * (2.0f * LOG2E);

    const float4* xr = (const float4*)(x + (size_t)b * T);
    int nT4 = T >> 2;
    float4 xv = xr[0];
    for (int t4 = 0; t4 < nT4; ++t4) {
        float4 nxt = (t4 + 1 < nT4) ? xr[t4 + 1] : xv;   // prefetch next chunk
        lstm_step(xv.x, h, cs, Cf);
        lstm_step(xv.y, h, cs, Cf);
        lstm_step(xv.z, h, cs, Cf);
        lstm_step(xv.w, h, cs, Cf);
        xv = nxt;
    }

    // backward direction: exactly one step on x[:, T-1]
    Ctx Cb;
    load_ctx(Cb, j, qp, w_ih_b, w_hh_b, b_b);
    float hb  = h0[(size_t)B * 8 + (size_t)b * 8 + j];
    float cbs = c0[(size_t)B * 8 + (size_t)b * 8 + j] * (2.0f * LOG2E);
    float xlast = x[(size_t)b * T + (T - 1)];
    lstm_step(xlast, hb, cbs, Cb);

    // final linear: out[b] = sum_j h[j]*wl[j] + hb[j]*wl[8+j] + b_lin
    float part = fmaf(h, w_lin[j], hb * w_lin[8 + j]);
    part += __shfl_xor(part, 1, 8);
    part += __shfl_xor(part, 2, 8);
    part += __shfl_xor(part, 4, 8);
    if (j == 0) out[b] = part + b_lin[0];
}

extern "C" void kernel_launch(void* const* d_in, const int* in_sizes, int n_in,
                              void* d_out, int out_size, void* d_ws, size_t ws_size,
                              hipStream_t stream)
{
    const float* x      = (const float*)d_in[0];
    const float* h0     = (const float*)d_in[1];
    const float* c0     = (const float*)d_in[2];
    const float* w_ih_f = (const float*)d_in[3];
    const float* w_hh_f = (const float*)d_in[4];
    const float* b_f    = (const float*)d_in[5];
    const float* w_ih_b = (const float*)d_in[6];
    const float* w_hh_b = (const float*)d_in[7];
    const float* b_b    = (const float*)d_in[8];
    const float* w_lin  = (const float*)d_in[9];
    const float* b_lin  = (const float*)d_in[10];
    float* out = (float*)d_out;

    int B = in_sizes[1] / 16;   // h0: (2, B, 8)
    int T = in_sizes[0] / B;    // x:  (B, T, 1)

    int threads = B * 8;
    dim3 block(256);
    dim3 grid((threads + 255) / 256);
    hipLaunchKernelGGL(bilstm_kernel, grid, block, 0, stream,
                       x, h0, c0, w_ih_f, w_hh_f, b_f, w_ih_b, w_hh_b, b_b,
                       w_lin, b_lin, out, B, T);
}

// Round 7
// 135.451 us; speedup vs baseline: 1.3755x; 1.0854x over previous
//
#include <hip/hip_runtime.h>

// Bidirectional LSTM, B=16384 T=512 I=1 H=8, + final linear on [h_f(T-1), h_b(T-1)].
// Backward direction's state at time T-1 is its FIRST scan step -> one step only.
//
// R7 = R1 structure (8 lanes/elem, broadcast on the DS pipe, scalar fma,
// hardware v_exp/v_rcp, compiler-scheduled) with:
//  1. Trans ops 10 -> 8 per step (R6-validated math): activation scales folded
//     into weights (i,f,o rows x -log2e; g row x +2log2e), paired reciprocals
//     (1 rcp serves 2 gates), cell state kept pre-scaled by 2log2e.
//  2. Hybrid broadcast: slots 0-3 = own-quad h via quad_perm DPP (VALU, ready
//     immediately -> fma chains start while DS flies); slots 4-7 = cross-quad h
//     via 4 bit-mode ds_swizzles (and=0x1C keeps quad parity: each quad pulls
//     the OTHER quad's 4 values). DS ops per step 8 -> 4, off the VALU pipe.
//     Slot->h-index: k<4 -> qp*4+k ; k>=4 -> (1-qp)*4 + (k-4). Compensated by
//     scalar-index weight permutation at setup (no arrays -> no scratch).
//  3. No x prefetch (the conditional float4 prefetch caused 2 MB scratch spill
//     in R4/R6 - WRITE_SIZE 2112 KB).

#define LOG2E 1.4426950408889634f

// quad_perm broadcast k within each 4-lane quad (k = 0..3): ctrl = k * 0x55
#define DPPQ(v, k) __int_as_float(__builtin_amdgcn_update_dpp(0, __float_as_int(v), ((k) * 0x55), 0xF, 0xF, true))
// cross-quad pull: src = ((i & 0x1C) | k) ^ 4  -> quad0 gets h[4+k], quad1 gets h[k]
#define SWZX(v, k) __int_as_float(__builtin_amdgcn_ds_swizzle(__float_as_int(v), ((4 << 10) | ((k) << 5) | 0x1C)))

struct Ctx {
    float wi[8], wf[8], wg[8], wo[8];  // recurrent rows, pre-scaled + slot-permuted
    float xi, xf, xg, xo;              // input weights, pre-scaled
    float bi, bf, bg, bo;              // biases, pre-scaled
};

__device__ __forceinline__ void load_ctx(Ctx& C, int j, int qp,
    const float* __restrict__ w_ih, const float* __restrict__ w_hh,
    const float* __restrict__ b)
{
    // slot k -> h index: k<4 -> qp*4+k ; k>=4 -> (1-qp)*4 + (k-4)
    int own = qp * 4;
    int oth = 4 - own;
    const float si = -LOG2E;           // sigma rows: e = exp2(-z*log2e) = e^-z
    const float sg = 2.0f * LOG2E;     // tanh row:  e = exp2(2z*log2e) = e^{2z}

    const float* ri = w_hh + (size_t)j * 8;
    const float* rf = w_hh + (size_t)(8 + j) * 8;
    const float* rg = w_hh + (size_t)(16 + j) * 8;
    const float* ro = w_hh + (size_t)(24 + j) * 8;
#pragma unroll
    for (int k = 0; k < 8; ++k) {
        int src = (k < 4) ? (own + k) : (oth + k - 4);
        C.wi[k] = ri[src] * si;
        C.wf[k] = rf[src] * si;
        C.wg[k] = rg[src] * sg;
        C.wo[k] = ro[src] * si;
    }
    C.xi = w_ih[j] * si;      C.bi = b[j] * si;
    C.xf = w_ih[8 + j] * si;  C.bf = b[8 + j] * si;
    C.xg = w_ih[16 + j] * sg; C.bg = b[16 + j] * sg;
    C.xo = w_ih[24 + j] * si; C.bo = b[24 + j] * si;
}

// cs is the cell state pre-scaled by 2*log2(e).
__device__ __forceinline__ void lstm_step(float xt, float& h, float& cs, const Ctx& C)
{
    // slots 4-7: cross-quad values via DS pipe (issue first, latency hidden
    // under the DPP slots' fma work)
    float hk4 = SWZX(h, 0);
    float hk5 = SWZX(h, 1);
    float hk6 = SWZX(h, 2);
    float hk7 = SWZX(h, 3);
    // slots 0-3: own-quad values via quad_perm DPP (ready immediately)
    float hk0 = DPPQ(h, 0);
    float hk1 = DPPQ(h, 1);
    float hk2 = DPPQ(h, 2);
    float hk3 = DPPQ(h, 3);

    float zi = fmaf(xt, C.xi, C.bi);
    float zf = fmaf(xt, C.xf, C.bf);
    float zg = fmaf(xt, C.xg, C.bg);
    float zo = fmaf(xt, C.xo, C.bo);

    zi = fmaf(hk0, C.wi[0], zi); zf = fmaf(hk0, C.wf[0], zf);
    zg = fmaf(hk0, C.wg[0], zg); zo = fmaf(hk0, C.wo[0], zo);
    zi = fmaf(hk1, C.wi[1], zi); zf = fmaf(hk1, C.wf[1], zf);
    zg = fmaf(hk1, C.wg[1], zg); zo = fmaf(hk1, C.wo[1], zo);
    zi = fmaf(hk2, C.wi[2], zi); zf = fmaf(hk2, C.wf[2], zf);
    zg = fmaf(hk2, C.wg[2], zg); zo = fmaf(hk2, C.wo[2], zo);
    zi = fmaf(hk3, C.wi[3], zi); zf = fmaf(hk3, C.wf[3], zf);
    zg = fmaf(hk3, C.wg[3], zg); zo = fmaf(hk3, C.wo[3], zo);
    zi = fmaf(hk4, C.wi[4], zi); zf = fmaf(hk4, C.wf[4], zf);
    zg = fmaf(hk4, C.wg[4], zg); zo = fmaf(hk4, C.wo[4], zo);
    zi = fmaf(hk5, C.wi[5], zi); zf = fmaf(hk5, C.wf[5], zf);
    zg = fmaf(hk5, C.wg[5], zg); zo = fmaf(hk5, C.wo[5], zo);
    zi = fmaf(hk6, C.wi[6], zi); zf = fmaf(hk6, C.wf[6], zf);
    zg = fmaf(hk6, C.wg[6], zg); zo = fmaf(hk6, C.wo[6], zo);
    zi = fmaf(hk7, C.wi[7], zi); zf = fmaf(hk7, C.wf[7], zf);
    zg = fmaf(hk7, C.wg[7], zg); zo = fmaf(hk7, C.wo[7], zo);

    float ei = __builtin_amdgcn_exp2f(zi);   // e^{-i}
    float ef = __builtin_amdgcn_exp2f(zf);   // e^{-f}
    float eg = __builtin_amdgcn_exp2f(zg);   // e^{2g}
    float eo = __builtin_amdgcn_exp2f(zo);   // e^{-o}
    float di = 1.0f + ei, df = 1.0f + ef;
    float dg = 1.0f + eg, dz = 1.0f + eo;

    // paired reciprocals: 2 rcp for 4 gates
    float Ra = __builtin_amdgcn_rcpf(di * df);
    float sigi = Ra * df;                    // sigma(i)
    float sigf = Ra * di;                    // sigma(f)
    float Rb = __builtin_amdgcn_rcpf(dg * dz);
    float qg   = Rb * dz;                    // 1/(1+e^{2g})
    float sigo = Rb * dg;                    // sigma(o)

    // tgs = 2*log2(e) * tanh(g)
    float tgs = fmaf(-4.0f * LOG2E, qg, 2.0f * LOG2E);
    cs = fmaf(sigf, cs, sigi * tgs);         // scaled cell update
    // tanh(c) = 1 - 2/(1+e^{2c}), and e^{2c} = exp2(cs)
    float ec = __builtin_amdgcn_exp2f(cs);
    float qc = __builtin_amdgcn_rcpf(1.0f + ec);
    h = sigo * fmaf(-2.0f, qc, 1.0f);
}

__global__ __launch_bounds__(256, 2) void bilstm_kernel(
    const float* __restrict__ x, const float* __restrict__ h0, const float* __restrict__ c0,
    const float* __restrict__ w_ih_f, const float* __restrict__ w_hh_f, const float* __restrict__ b_f,
    const float* __restrict__ w_ih_b, const float* __restrict__ w_hh_b, const float* __restrict__ b_b,
    const float* __restrict__ w_lin, const float* __restrict__ b_lin,
    float* __restrict__ out, int B, int T)
{
    int tid = blockIdx.x * 256 + threadIdx.x;
    int b = tid >> 3;
    int j = tid & 7;
    int qp = (threadIdx.x >> 2) & 1;   // quad parity within the 8-lane group
    if (b >= B) return;

    Ctx Cf;
    load_ctx(Cf, j, qp, w_ih_f, w_hh_f, b_f);

    float h  = h0[(size_t)b * 8 + j];
    float cs = c0[(size_t)b * 8 + j] * (2.0f * LOG2E);

    const float4* xr = (const float4*)(x + (size_t)b * T);
    int nT4 = T >> 2;
    for (int t4 = 0; t4 < nT4; ++t4) {
        float4 xv = xr[t4];
        lstm_step(xv.x, h, cs, Cf);
        lstm_step(xv.y, h, cs, Cf);
        lstm_step(xv.z, h, cs, Cf);
        lstm_step(xv.w, h, cs, Cf);
    }

    // backward direction: exactly one step on x[:, T-1]
    Ctx Cb;
    load_ctx(Cb, j, qp, w_ih_b, w_hh_b, b_b);
    float hb  = h0[(size_t)B * 8 + (size_t)b * 8 + j];
    float cbs = c0[(size_t)B * 8 + (size_t)b * 8 + j] * (2.0f * LOG2E);
    float xlast = x[(size_t)b * T + (T - 1)];
    lstm_step(xlast, hb, cbs, Cb);

    // final linear: out[b] = sum_j h[j]*wl[j] + hb[j]*wl[8+j] + b_lin
    float part = fmaf(h, w_lin[j], hb * w_lin[8 + j]);
    part += __shfl_xor(part, 1, 8);
    part += __shfl_xor(part, 2, 8);
    part += __shfl_xor(part, 4, 8);
    if (j == 0) out[b] = part + b_lin[0];
}

extern "C" void kernel_launch(void* const* d_in, const int* in_sizes, int n_in,
                              void* d_out, int out_size, void* d_ws, size_t ws_size,
                              hipStream_t stream)
{
    const float* x      = (const float*)d_in[0];
    const float* h0     = (const float*)d_in[1];
    const float* c0     = (const float*)d_in[2];
    const float* w_ih_f = (const float*)d_in[3];
    const float* w_hh_f = (const float*)d_in[4];
    const float* b_f    = (const float*)d_in[5];
    const float* w_ih_b = (const float*)d_in[6];
    const float* w_hh_b = (const float*)d_in[7];
    const float* b_b    = (const float*)d_in[8];
    const float* w_lin  = (const float*)d_in[9];
    const float* b_lin  = (const float*)d_in[10];
    float* out = (float*)d_out;

    int B = in_sizes[1] / 16;   // h0: (2, B, 8)
    int T = in_sizes[0] / B;    // x:  (B, T, 1)

    int threads = B * 8;
    dim3 block(256);
    dim3 grid((threads + 255) / 256);
    hipLaunchKernelGGL(bilstm_kernel, grid, block, 0, stream,
                       x, h0, c0, w_ih_f, w_hh_f, b_f, w_ih_b, w_hh_b, b_b,
                       w_lin, b_lin, out, B, T);
}

// Round 8
// 127.617 us; speedup vs baseline: 1.4599x; 1.0614x over previous
//
#include <hip/hip_runtime.h>

// Bidirectional LSTM, B=16384 T=512 I=1 H=8, + final linear on [h_f(T-1), h_b(T-1)].
// Backward direction's state at time T-1 is its FIRST scan step -> one step only.
//
// R8 = R7 + software-pipelined x prefetch.
//  R7 core (kept): 8 lanes/elem; hybrid h-broadcast (4 own-quad quad_perm DPP +
//  4 cross-quad bit-mode ds_swizzles -> DS latency hidden under DPP-fed fma
//  chains); trans 10->8 per step (scales folded into weights, paired rcp,
//  cell pre-scaled by 2log2e); scalar fma, compiler-scheduled.
//  New: the float4 x-load for group t4+1 is issued UNCONDITIONALLY at the top
//  of iteration t4 (loop runs nT4-1 iters + peeled epilogue). R1/R7 exposed
//  ~300-500 cyc of load latency once per 4 steps (~110 idle cyc/step = the
//  VALUBusy gap); R4/R6's conditional-ternary prefetch spilled to scratch
//  (WRITE_SIZE 2112 KB). Unconditional load -> no select -> no spill.

#define LOG2E 1.4426950408889634f

// quad_perm broadcast k within each 4-lane quad (k = 0..3): ctrl = k * 0x55
#define DPPQ(v, k) __int_as_float(__builtin_amdgcn_update_dpp(0, __float_as_int(v), ((k) * 0x55), 0xF, 0xF, true))
// cross-quad pull: src = ((i & 0x1C) | k) ^ 4  -> quad0 gets h[4+k], quad1 gets h[k]
#define SWZX(v, k) __int_as_float(__builtin_amdgcn_ds_swizzle(__float_as_int(v), ((4 << 10) | ((k) << 5) | 0x1C)))

struct Ctx {
    float wi[8], wf[8], wg[8], wo[8];  // recurrent rows, pre-scaled + slot-permuted
    float xi, xf, xg, xo;              // input weights, pre-scaled
    float bi, bf, bg, bo;              // biases, pre-scaled
};

__device__ __forceinline__ void load_ctx(Ctx& C, int j, int qp,
    const float* __restrict__ w_ih, const float* __restrict__ w_hh,
    const float* __restrict__ b)
{
    // slot k -> h index: k<4 -> qp*4+k ; k>=4 -> (1-qp)*4 + (k-4)
    int own = qp * 4;
    int oth = 4 - own;
    const float si = -LOG2E;           // sigma rows: e = exp2(-z*log2e) = e^-z
    const float sg = 2.0f * LOG2E;     // tanh row:  e = exp2(2z*log2e) = e^{2z}

    const float* ri = w_hh + (size_t)j * 8;
    const float* rf = w_hh + (size_t)(8 + j) * 8;
    const float* rg = w_hh + (size_t)(16 + j) * 8;
    const float* ro = w_hh + (size_t)(24 + j) * 8;
#pragma unroll
    for (int k = 0; k < 8; ++k) {
        int src = (k < 4) ? (own + k) : (oth + k - 4);
        C.wi[k] = ri[src] * si;
        C.wf[k] = rf[src] * si;
        C.wg[k] = rg[src] * sg;
        C.wo[k] = ro[src] * si;
    }
    C.xi = w_ih[j] * si;      C.bi = b[j] * si;
    C.xf = w_ih[8 + j] * si;  C.bf = b[8 + j] * si;
    C.xg = w_ih[16 + j] * sg; C.bg = b[16 + j] * sg;
    C.xo = w_ih[24 + j] * si; C.bo = b[24 + j] * si;
}

// cs is the cell state pre-scaled by 2*log2(e).
__device__ __forceinline__ void lstm_step(float xt, float& h, float& cs, const Ctx& C)
{
    // slots 4-7: cross-quad values via DS pipe (issue first, latency hidden
    // under the DPP slots' fma work)
    float hk4 = SWZX(h, 0);
    float hk5 = SWZX(h, 1);
    float hk6 = SWZX(h, 2);
    float hk7 = SWZX(h, 3);
    // slots 0-3: own-quad values via quad_perm DPP (ready immediately)
    float hk0 = DPPQ(h, 0);
    float hk1 = DPPQ(h, 1);
    float hk2 = DPPQ(h, 2);
    float hk3 = DPPQ(h, 3);

    float zi = fmaf(xt, C.xi, C.bi);
    float zf = fmaf(xt, C.xf, C.bf);
    float zg = fmaf(xt, C.xg, C.bg);
    float zo = fmaf(xt, C.xo, C.bo);

    zi = fmaf(hk0, C.wi[0], zi); zf = fmaf(hk0, C.wf[0], zf);
    zg = fmaf(hk0, C.wg[0], zg); zo = fmaf(hk0, C.wo[0], zo);
    zi = fmaf(hk1, C.wi[1], zi); zf = fmaf(hk1, C.wf[1], zf);
    zg = fmaf(hk1, C.wg[1], zg); zo = fmaf(hk1, C.wo[1], zo);
    zi = fmaf(hk2, C.wi[2], zi); zf = fmaf(hk2, C.wf[2], zf);
    zg = fmaf(hk2, C.wg[2], zg); zo = fmaf(hk2, C.wo[2], zo);
    zi = fmaf(hk3, C.wi[3], zi); zf = fmaf(hk3, C.wf[3], zf);
    zg = fmaf(hk3, C.wg[3], zg); zo = fmaf(hk3, C.wo[3], zo);
    zi = fmaf(hk4, C.wi[4], zi); zf = fmaf(hk4, C.wf[4], zf);
    zg = fmaf(hk4, C.wg[4], zg); zo = fmaf(hk4, C.wo[4], zo);
    zi = fmaf(hk5, C.wi[5], zi); zf = fmaf(hk5, C.wf[5], zf);
    zg = fmaf(hk5, C.wg[5], zg); zo = fmaf(hk5, C.wo[5], zo);
    zi = fmaf(hk6, C.wi[6], zi); zf = fmaf(hk6, C.wf[6], zf);
    zg = fmaf(hk6, C.wg[6], zg); zo = fmaf(hk6, C.wo[6], zo);
    zi = fmaf(hk7, C.wi[7], zi); zf = fmaf(hk7, C.wf[7], zf);
    zg = fmaf(hk7, C.wg[7], zg); zo = fmaf(hk7, C.wo[7], zo);

    float ei = __builtin_amdgcn_exp2f(zi);   // e^{-i}
    float ef = __builtin_amdgcn_exp2f(zf);   // e^{-f}
    float eg = __builtin_amdgcn_exp2f(zg);   // e^{2g}
    float eo = __builtin_amdgcn_exp2f(zo);   // e^{-o}
    float di = 1.0f + ei, df = 1.0f + ef;
    float dg = 1.0f + eg, dz = 1.0f + eo;

    // paired reciprocals: 2 rcp for 4 gates
    float Ra = __builtin_amdgcn_rcpf(di * df);
    float sigi = Ra * df;                    // sigma(i)
    float sigf = Ra * di;                    // sigma(f)
    float Rb = __builtin_amdgcn_rcpf(dg * dz);
    float qg   = Rb * dz;                    // 1/(1+e^{2g})
    float sigo = Rb * dg;                    // sigma(o)

    // tgs = 2*log2(e) * tanh(g)
    float tgs = fmaf(-4.0f * LOG2E, qg, 2.0f * LOG2E);
    cs = fmaf(sigf, cs, sigi * tgs);         // scaled cell update
    // tanh(c) = 1 - 2/(1+e^{2c}), and e^{2c} = exp2(cs)
    float ec = __builtin_amdgcn_exp2f(cs);
    float qc = __builtin_amdgcn_rcpf(1.0f + ec);
    h = sigo * fmaf(-2.0f, qc, 1.0f);
}

__global__ __launch_bounds__(256, 2) void bilstm_kernel(
    const float* __restrict__ x, const float* __restrict__ h0, const float* __restrict__ c0,
    const float* __restrict__ w_ih_f, const float* __restrict__ w_hh_f, const float* __restrict__ b_f,
    const float* __restrict__ w_ih_b, const float* __restrict__ w_hh_b, const float* __restrict__ b_b,
    const float* __restrict__ w_lin, const float* __restrict__ b_lin,
    float* __restrict__ out, int B, int T)
{
    int tid = blockIdx.x * 256 + threadIdx.x;
    int b = tid >> 3;
    int j = tid & 7;
    int qp = (threadIdx.x >> 2) & 1;   // quad parity within the 8-lane group
    if (b >= B) return;

    Ctx Cf;
    load_ctx(Cf, j, qp, w_ih_f, w_hh_f, b_f);

    float h  = h0[(size_t)b * 8 + j];
    float cs = c0[(size_t)b * 8 + j] * (2.0f * LOG2E);

    const float4* xr = (const float4*)(x + (size_t)b * T);
    int nT4 = T >> 2;
    float4 xv = xr[0];
    // software pipeline: load group t4+1 unconditionally, use group t4
    for (int t4 = 0; t4 < nT4 - 1; ++t4) {
        float4 nxt = xr[t4 + 1];
        lstm_step(xv.x, h, cs, Cf);
        lstm_step(xv.y, h, cs, Cf);
        lstm_step(xv.z, h, cs, Cf);
        lstm_step(xv.w, h, cs, Cf);
        xv = nxt;
    }
    // epilogue: last group
    lstm_step(xv.x, h, cs, Cf);
    lstm_step(xv.y, h, cs, Cf);
    lstm_step(xv.z, h, cs, Cf);
    float xlast = xv.w;
    lstm_step(xlast, h, cs, Cf);

    // backward direction: exactly one step on x[:, T-1] (== xv.w)
    Ctx Cb;
    load_ctx(Cb, j, qp, w_ih_b, w_hh_b, b_b);
    float hb  = h0[(size_t)B * 8 + (size_t)b * 8 + j];
    float cbs = c0[(size_t)B * 8 + (size_t)b * 8 + j] * (2.0f * LOG2E);
    lstm_step(xlast, hb, cbs, Cb);

    // final linear: out[b] = sum_j h[j]*wl[j] + hb[j]*wl[8+j] + b_lin
    float part = fmaf(h, w_lin[j], hb * w_lin[8 + j]);
    part += __shfl_xor(part, 1, 8);
    part += __shfl_xor(part, 2, 8);
    part += __shfl_xor(part, 4, 8);
    if (j == 0) out[b] = part + b_lin[0];
}

extern "C" void kernel_launch(void* const* d_in, const int* in_sizes, int n_in,
                              void* d_out, int out_size, void* d_ws, size_t ws_size,
                              hipStream_t stream)
{
    const float* x      = (const float*)d_in[0];
    const float* h0     = (const float*)d_in[1];
    const float* c0     = (const float*)d_in[2];
    const float* w_ih_f = (const float*)d_in[3];
    const float* w_hh_f = (const float*)d_in[4];
    const float* b_f    = (const float*)d_in[5];
    const float* w_ih_b = (const float*)d_in[6];
    const float* w_hh_b = (const float*)d_in[7];
    const float* b_b    = (const float*)d_in[8];
    const float* w_lin  = (const float*)d_in[9];
    const float* b_lin  = (const float*)d_in[10];
    float* out = (float*)d_out;

    int B = in_sizes[1] / 16;   // h0: (2, B, 8)
    int T = in_sizes[0] / B;    // x:  (B, T, 1)

    int threads = B * 8;
    dim3 block(256);
    dim3 grid((threads + 255) / 256);
    hipLaunchKernelGGL(bilstm_kernel, grid, block, 0, stream,
                       x, h0, c0, w_ih_f, w_hh_f, b_f, w_ih_b, w_hh_b, b_b,
                       w_lin, b_lin, out, B, T);
}